// Round 7
// baseline (522.101 us; speedup 1.0000x reference)
//
#include <hip/hip_runtime.h>
#include <cmath>

#define DEV __device__ __forceinline__

constexpr int B_SZ = 16;
constexpr int LSEQ = 256;
constexpr int DM   = 256;   // d_model
constexpr int DI   = 512;   // d_inner
constexpr int TLEN = 16;

DEV float silu_f(float x)     { return x / (1.f + __expf(-x)); }
DEV float softplus_f(float x) { return log1pf(__expf(x)); }

// ---------------------------------------------------------------------------
// kA: blocks [0,128): fold WcT[k][newc] = (W_in·W_out)^T in gen-sliced layout
//     blocks [128,640): in-projection xi_pre = x^T @ W_in(x-part)^T
// ---------------------------------------------------------------------------
__global__ __launch_bounds__(256) void k_prefill_a(const float* __restrict__ x,
                                                   const float* __restrict__ W_in,
                                                   const float* __restrict__ W_out,
                                                   float* __restrict__ WcT,
                                                   float* __restrict__ xi_pre) {
    __shared__ float smem[2][32][68];
    const int tid = threadIdx.x;
    const int ty = tid >> 4, tx = tid & 15;
    float acc[4][4] = {};
    if (blockIdx.x < 128) {
        const int j0 = (int)(blockIdx.x & 15) * 64;
        const int d0 = (int)(blockIdx.x >> 4) * 64;
        float (*As)[68] = smem[0];
        float (*Bs)[68] = smem[1];
        for (int kc = 0; kc < DM; kc += 32) {
            for (int it = 0; it < 8; ++it) {
                int idx = it * 256 + tid;
                int jj = idx >> 5, kk = idx & 31;
                As[kk][jj] = W_in[(size_t)(j0 + jj) * DM + kc + kk];
            }
            for (int it = 0; it < 8; ++it) {
                int idx = it * 256 + tid;
                int kk = idx >> 6, dd = idx & 63;
                Bs[kk][dd] = W_out[(size_t)(kc + kk) * DI + d0 + dd];
            }
            __syncthreads();
            for (int kk = 0; kk < 32; ++kk) {
                float4 a4 = *(const float4*)&As[kk][ty * 4];
                float4 b4 = *(const float4*)&Bs[kk][tx * 4];
                float av[4] = {a4.x, a4.y, a4.z, a4.w};
                float bv[4] = {b4.x, b4.y, b4.z, b4.w};
                for (int i = 0; i < 4; ++i)
                    for (int j = 0; j < 4; ++j) acc[i][j] = fmaf(av[i], bv[j], acc[i][j]);
            }
            __syncthreads();
        }
        float (*Cs)[65] = (float(*)[65])&smem[0][0][0];
        for (int i = 0; i < 4; ++i)
            for (int j = 0; j < 4; ++j)
                Cs[ty * 4 + i][tx * 4 + j] = acc[i][j];
        __syncthreads();
        const int dr = tid >> 2, jq = tid & 3;
        for (int ii = 0; ii < 4; ++ii) {
            int jl = jq * 16 + ii * 4;
            int jg = j0 + jl;
            int newc;
            if (jg < DI) newc = (jg >> 5) * 64 + (jg & 31);
            else { int jz = jg - DI; newc = (jz >> 5) * 64 + 32 + (jz & 31); }
            float4 v = make_float4(Cs[jl][dr], Cs[jl + 1][dr], Cs[jl + 2][dr], Cs[jl + 3][dr]);
            *(float4*)&WcT[(size_t)(d0 + dr) * 1024 + newc] = v;
        }
    } else {
        const int bid2 = (int)blockIdx.x - 128;
        const int bx = bid2 & 7, by = bid2 >> 3;
        const int row0 = by * 64;
        const int b = row0 >> 8, l0 = row0 & 255;
        const int j0 = bx * 64;
        float (*As)[68] = smem[0];
        float (*Ws)[68] = smem[1];
        const float* xb = x + (size_t)b * DM * LSEQ;
        for (int kc = 0; kc < DM; kc += 32) {
            for (int it = 0; it < 8; ++it) {
                int idx = it * 256 + tid;
                int kk = idx >> 6, li = idx & 63;
                As[kk][li] = xb[(kc + kk) * LSEQ + l0 + li];
            }
            for (int it = 0; it < 8; ++it) {
                int idx = it * 256 + tid;
                int jj = idx >> 5, kk = idx & 31;
                Ws[kk][jj] = W_in[(size_t)(j0 + jj) * DM + kc + kk];
            }
            __syncthreads();
            for (int kk = 0; kk < 32; ++kk) {
                float4 a4 = *(const float4*)&As[kk][ty * 4];
                float4 w4 = *(const float4*)&Ws[kk][tx * 4];
                float av[4] = {a4.x, a4.y, a4.z, a4.w};
                float wv[4] = {w4.x, w4.y, w4.z, w4.w};
                for (int i = 0; i < 4; ++i)
                    for (int j = 0; j < 4; ++j) acc[i][j] = fmaf(av[i], wv[j], acc[i][j]);
            }
            __syncthreads();
        }
        for (int i = 0; i < 4; ++i) {
            float4 v = make_float4(acc[i][0], acc[i][1], acc[i][2], acc[i][3]);
            *(float4*)&xi_pre[(size_t)(row0 + ty * 4 + i) * DI + j0 + tx * 4] = v;
        }
    }
}

// ---------------------------------------------------------------------------
// kB: fused conv+silu -> dtBC GEMM -> chunked scan (unchanged).
// ---------------------------------------------------------------------------
__global__ __launch_bounds__(512) void k_prefill_b(const float* __restrict__ xi_pre,
                                                   const float* __restrict__ conv_w,
                                                   const float* __restrict__ conv_b,
                                                   const float* __restrict__ W_x,
                                                   const float* __restrict__ W_dt,
                                                   const float* __restrict__ b_dt,
                                                   const float* __restrict__ A_log,
                                                   float* __restrict__ Qb,
                                                   float* __restrict__ Sb,
                                                   float* __restrict__ dtBC255) {
    __shared__ float As[32][516];
    __shared__ float Ws[48][129];
    __shared__ float dt_s[32][49];
    const int blk = blockIdx.x;
    const int b = blk >> 3, c = blk & 7;
    const int d = threadIdx.x;
    const int l0 = c * 32;
    {
        const float c0 = conv_w[d * 4 + 0], c1 = conv_w[d * 4 + 1];
        const float c2 = conv_w[d * 4 + 2], c3 = conv_w[d * 4 + 3];
        const float cbv = conv_b[d];
        float p0, p1, p2;
        int l;
        l = l0 - 3; p0 = (l >= 0) ? xi_pre[(size_t)(b * 256 + l) * DI + d] : 0.f;
        l = l0 - 2; p1 = (l >= 0) ? xi_pre[(size_t)(b * 256 + l) * DI + d] : 0.f;
        l = l0 - 1; p2 = (l >= 0) ? xi_pre[(size_t)(b * 256 + l) * DI + d] : 0.f;
        for (int ll = 0; ll < 32; ++ll) {
            float v = xi_pre[(size_t)(b * 256 + l0 + ll) * DI + d];
            As[ll][d] = silu_f(cbv + c0 * p0 + c1 * p1 + c2 * p2 + c3 * v);
            p0 = p1; p1 = p2; p2 = v;
        }
    }
    __syncthreads();
    {
        const int lr = d >> 4, rg = d & 15;
        float acc[3] = {};
        for (int kc = 0; kc < 4; ++kc) {
            for (int it = 0; it < 12; ++it) {
                int idx = it * 512 + d;
                int rr = idx >> 7, k = idx & 127;
                Ws[rr][k] = W_x[(size_t)rr * DI + kc * 128 + k];
            }
            __syncthreads();
            for (int k = 0; k < 128; ++k) {
                float a = As[lr][kc * 128 + k];
                acc[0] = fmaf(a, Ws[rg * 3 + 0][k], acc[0]);
                acc[1] = fmaf(a, Ws[rg * 3 + 1][k], acc[1]);
                acc[2] = fmaf(a, Ws[rg * 3 + 2][k], acc[2]);
            }
            __syncthreads();
        }
        dt_s[lr][rg * 3 + 0] = acc[0];
        dt_s[lr][rg * 3 + 1] = acc[1];
        dt_s[lr][rg * 3 + 2] = acc[2];
    }
    __syncthreads();
    {
        float Ar[16], Wd[16];
        for (int n = 0; n < 16; ++n) Ar[n] = -__expf(A_log[d * 16 + n]);
        for (int r = 0; r < 16; ++r) Wd[r] = W_dt[d * 16 + r];
        const float bd = b_dt[d];
        float q[16] = {};
        float Ssum = 0.f;
        for (int l = 0; l < 32; ++l) {
            float s = bd;
            for (int r = 0; r < 16; ++r) s = fmaf(dt_s[l][r], Wd[r], s);
            const float del = softplus_f(s);
            const float u = As[l][d];
            const float du = del * u;
            Ssum += del;
            for (int n = 0; n < 16; ++n) {
                float dA = __expf(del * Ar[n]);
                q[n] = fmaf(dA, q[n], du * dt_s[l][16 + n]);
            }
        }
        float* qo = Qb + ((size_t)blk * DI + d) * 16;
        for (int n = 0; n < 16; ++n) qo[n] = q[n];
        Sb[blk * DI + d] = Ssum;
    }
    if (c == 7 && d < 48) dtBC255[b * 48 + d] = dt_s[31][d];
}

// ---------------------------------------------------------------------------
// kC: compose chunks -> h(255), z(255) inline, gate -> gbuf (unchanged).
// ---------------------------------------------------------------------------
__global__ __launch_bounds__(512) void k_prefill_c(const float* __restrict__ x,
                                                   const float* __restrict__ W_in,
                                                   const float* __restrict__ Qb,
                                                   const float* __restrict__ Sb,
                                                   const float* __restrict__ dtBC255,
                                                   const float* __restrict__ xi_pre,
                                                   const float* __restrict__ conv_w,
                                                   const float* __restrict__ conv_b,
                                                   const float* __restrict__ A_log,
                                                   const float* __restrict__ Dp,
                                                   float* __restrict__ h_state,
                                                   float* __restrict__ gbuf) {
    __shared__ __align__(16) float xcol[256];
    const int b = blockIdx.x;
    const int d = threadIdx.x;
    if (d < 256) xcol[d] = x[(size_t)b * DM * LSEQ + d * LSEQ + 255];
    __syncthreads();
    float z = 0.f;
    {
        const float4* wr = (const float4*)&W_in[(size_t)(DI + d) * DM];
        const float4* xc4 = (const float4*)xcol;
        for (int k = 0; k < 64; ++k) {
            float4 w = wr[k], xx = xc4[k];
            z += w.x * xx.x + w.y * xx.y + w.z * xx.z + w.w * xx.w;
        }
    }
    float Ar[16];
    for (int n = 0; n < 16; ++n) Ar[n] = -__expf(A_log[d * 16 + n]);
    float h[16] = {};
    for (int c = 0; c < 8; ++c) {
        const int blk = b * 8 + c;
        const float S = Sb[blk * DI + d];
        const float* qv = Qb + ((size_t)blk * DI + d) * 16;
        for (int n = 0; n < 16; ++n) {
            float P = __expf(S * Ar[n]);
            h[n] = fmaf(P, h[n], qv[n]);
        }
    }
    float y = 0.f;
    for (int n = 0; n < 16; ++n) y = fmaf(h[n], dtBC255[b * 48 + 32 + n], y);
    float u;
    {
        float s = conv_b[d];
        for (int k = 0; k < 4; ++k)
            s = fmaf(conv_w[d * 4 + k], xi_pre[(size_t)(b * 256 + 252 + k) * DI + d], s);
        u = silu_f(s);
    }
    y = fmaf(u, Dp[d], y);
    gbuf[b * DI + d] = y * silu_f(z);
    float* ho = h_state + ((size_t)(b * DI + d)) * 16;
    for (int n = 0; n < 16; ++n) ho[n] = h[n];
}

// ---------------------------------------------------------------------------
// kD: persistent generation. 256 blocks = 16 batches x 16 slices, 512 thr.
// wc pinned regs (staged LAST); wout in LDS; partial dtBC (7KB W_x slice)
// exchanged in the single 112-float post; relaxed poll + one acquire fence;
// scan reads dtbc as float4 broadcasts.
// ---------------------------------------------------------------------------
__global__ __launch_bounds__(512, 2) void k_gen(
    const float* __restrict__ WcT, const float* __restrict__ W_out,
    const float* __restrict__ W_x, const float* __restrict__ W_dt,
    const float* __restrict__ conv_w, const float* __restrict__ conv_b,
    const float* __restrict__ b_dt, const float* __restrict__ A_log,
    const float* __restrict__ Dp, const float* __restrict__ xi_pre,
    const float* __restrict__ h_state, const float* __restrict__ gbuf0,
    float* __restrict__ xbuf, unsigned* __restrict__ flags,
    float* __restrict__ out) {
    const int bid = blockIdx.x;
    const int b = bid & 15;
    const int p = bid >> 4;
    const int tid = threadIdx.x;

    __shared__ float wxp[48][37];               // W_x cols [p*32,p*32+32)
    __shared__ float wout_s[16][516];           // W_out rows [p*16,p*16+16)
    __shared__ __align__(16) float gs_s[512];
    __shared__ float xin_s[512];
    __shared__ float zs_s[512];
    __shared__ float red8[8][68];
    __shared__ float dpart[16][52];
    __shared__ __align__(16) float dtbc_s[48];
    __shared__ float post_s[112];
    __shared__ float hist[3][32];

    // ---- phase 0: LDS staging first (keep pressure low before wc) ----
    for (int it = 0; it < 3; ++it) {
        int flat = it * 512 + tid;              // 1536 elems
        int rr = flat >> 5, cc = flat & 31;
        wxp[rr][cc] = W_x[(size_t)rr * DI + p * 32 + cc];
    }
    for (int it = 0; it < 16; ++it) {
        int flat = it * 512 + tid;              // 8192 elems
        int row = flat >> 9, col = flat & 511;
        wout_s[row][col] = W_out[(size_t)(p * 16 + row) * DI + col];
    }
    // scalar params
    const float bd = b_dt[tid];
    const float Dpv = Dp[tid];
    float cw0 = 0, cw1 = 0, cw2 = 0, cw3 = 0, cb = 0;
    if (tid < 32) {
        const int d = p * 32 + tid;
        cw0 = conv_w[d * 4 + 0]; cw1 = conv_w[d * 4 + 1];
        cw2 = conv_w[d * 4 + 2]; cw3 = conv_w[d * 4 + 3];
        cb  = conv_b[d];
        for (int k = 0; k < 3; ++k)
            hist[k][tid] = xi_pre[(size_t)(b * 256 + 253 + k) * DI + d];
    }
    gs_s[tid] = gbuf0[b * DI + tid];
    // per-thread scan state
    float wdt[16], Ar[16], h[16];
    {
        const float4* wp = (const float4*)&W_dt[tid * 16];
        const float4* ap = (const float4*)&A_log[tid * 16];
        const float4* hp = (const float4*)&h_state[((size_t)(b * DI + tid)) * 16];
        #pragma unroll
        for (int i = 0; i < 4; ++i) {
            float4 wv = wp[i], av = ap[i], hv = hp[i];
            wdt[4*i+0]=wv.x; wdt[4*i+1]=wv.y; wdt[4*i+2]=wv.z; wdt[4*i+3]=wv.w;
            Ar[4*i+0]=-__expf(av.x); Ar[4*i+1]=-__expf(av.y);
            Ar[4*i+2]=-__expf(av.z); Ar[4*i+3]=-__expf(av.w);
            h[4*i+0]=hv.x; h[4*i+1]=hv.y; h[4*i+2]=hv.z; h[4*i+3]=hv.w;
        }
    }
    #pragma unroll
    for (int i = 0; i < 16; ++i) asm volatile("" : "+v"(wdt[i]));

    // ---- phase 1: Wc slice into registers LAST (minimize overlap pressure)
    __builtin_amdgcn_sched_barrier(0);
    const int r = tid & 63, w = tid >> 6;
    float wc[64];
    {
        const float* src = WcT + (size_t)(w * 64) * 1024 + p * 64 + r;
        #pragma unroll
        for (int kk = 0; kk < 64; ++kk) wc[kk] = src[(size_t)kk * 1024];
    }
    #pragma unroll
    for (int kk = 0; kk < 64; ++kk) asm volatile("" : "+v"(wc[kk]));
    __builtin_amdgcn_sched_barrier(0);

    const int orow_l = tid >> 5, osub = tid & 31;
    __syncthreads();

    for (int t = 0; t < TLEN; ++t) {
        if (t < TLEN - 1) {
            // A: preconv GEMV — wc regs x gs b128 broadcasts
            {
                const float4* g4 = (const float4*)&gs_s[w * 64];
                float s = 0.f;
                #pragma unroll
                for (int kk = 0; kk < 16; ++kk) {
                    float4 g = g4[kk];
                    s = fmaf(wc[4*kk+0], g.x, s);
                    s = fmaf(wc[4*kk+1], g.y, s);
                    s = fmaf(wc[4*kk+2], g.z, s);
                    s = fmaf(wc[4*kk+3], g.w, s);
                }
                red8[w][r] = s;
            }
            __syncthreads();
            // B1: reduce; conv+silu / z -> post_s[0..64)
            if (tid < 64) {
                float v = 0.f;
                #pragma unroll
                for (int ss = 0; ss < 8; ++ss) v += red8[ss][tid];
                if (tid < 32) {
                    float xc = cb;
                    xc = fmaf(cw0, hist[t % 3][tid], xc);
                    xc = fmaf(cw1, hist[(t + 1) % 3][tid], xc);
                    xc = fmaf(cw2, hist[(t + 2) % 3][tid], xc);
                    xc = fmaf(cw3, v, xc);
                    hist[t % 3][tid] = v;
                    post_s[tid] = silu_f(xc);
                } else {
                    post_s[tid] = v;
                }
            }
            __syncthreads();
            // B2: own dtBC partial (48 rows x own 32 xin) -> post_s[64..112)
            if (tid < 384) {
                const int rr = tid >> 3, q = tid & 7;
                const float* wr = &wxp[rr][q * 4];
                const float* xv = &post_s[q * 4];
                float s = wr[0]*xv[0] + wr[1]*xv[1] + wr[2]*xv[2] + wr[3]*xv[3];
                s += __shfl_down(s, 4); s += __shfl_down(s, 2); s += __shfl_down(s, 1);
                if (q == 0) post_s[64 + rr] = s;
            }
            __syncthreads();
            // post 112 floats + release flag
            if (tid < 112) {
                __hip_atomic_store(&xbuf[((size_t)((b * 16 + p) * 2 + (t & 1))) * 128 + tid],
                                   post_s[tid], __ATOMIC_RELAXED, __HIP_MEMORY_SCOPE_AGENT);
            }
            __syncthreads();   // drain stores before flag
            if (tid == 0)
                __hip_atomic_store(&flags[b * 16 + p], (unsigned)(t + 1),
                                   __ATOMIC_RELEASE, __HIP_MEMORY_SCOPE_AGENT);
        }
        // C: output token t (wout LDS x gs broadcast; overlaps peers' posting)
        {
            float s = 0.f;
            #pragma unroll
            for (int j = 0; j < 16; ++j)
                s = fmaf(wout_s[orow_l][osub + 32 * j], gs_s[osub + 32 * j], s);
            s += __shfl_down(s, 16); s += __shfl_down(s, 8);
            s += __shfl_down(s, 4);  s += __shfl_down(s, 2); s += __shfl_down(s, 1);
            if (osub == 0) out[(size_t)(b * 256 + p * 16 + orow_l) * TLEN + t] = s;
        }
        if (t == TLEN - 1) return;

        // D: relaxed poll + single acquire fence
        if (tid < 16) {
            while (__hip_atomic_load(&flags[b * 16 + tid],
                                     __ATOMIC_RELAXED, __HIP_MEMORY_SCOPE_AGENT)
                   < (unsigned)(t + 1))
                __builtin_amdgcn_s_sleep(1);
        }
        __syncthreads();
        __builtin_amdgcn_fence(__ATOMIC_ACQUIRE, "agent");
        // E: gather 16 x 112
        #pragma unroll
        for (int i = 0; i < 4; ++i) {
            int idx = i * 512 + tid;
            int q = idx >> 7, pos = idx & 127;
            if (pos < 112) {
                float v = __hip_atomic_load(
                    xbuf + ((size_t)((b * 16 + q) * 2 + (t & 1))) * 128 + pos,
                    __ATOMIC_RELAXED, __HIP_MEMORY_SCOPE_AGENT);
                if (pos < 32)      xin_s[q * 32 + pos] = v;
                else if (pos < 64) zs_s[q * 32 + pos - 32] = v;
                else               dpart[q][pos - 64] = v;
            }
        }
        __syncthreads();
        // F: reduce dtbc partials
        if (tid < 48) {
            float s = 0.f;
            #pragma unroll
            for (int q = 0; q < 16; ++q) s += dpart[q][tid];
            dtbc_s[tid] = s;
        }
        __syncthreads();
        // G: replicated scan step (dtbc via float4 broadcasts)
        {
            const float4* dt4 = (const float4*)dtbc_s;
            float dt_l = bd;
            #pragma unroll
            for (int i = 0; i < 4; ++i) {
                float4 dv = dt4[i];
                dt_l = fmaf(dv.x, wdt[4*i+0], dt_l);
                dt_l = fmaf(dv.y, wdt[4*i+1], dt_l);
                dt_l = fmaf(dv.z, wdt[4*i+2], dt_l);
                dt_l = fmaf(dv.w, wdt[4*i+3], dt_l);
            }
            const float del = softplus_f(dt_l);
            const float u = xin_s[tid];
            const float du = del * u;
            float y = 0.f;
            #pragma unroll
            for (int nq = 0; nq < 4; ++nq) {
                float4 Bv = dt4[4 + nq];
                float4 Cv = dt4[8 + nq];
                float bb[4] = {Bv.x, Bv.y, Bv.z, Bv.w};
                float cc[4] = {Cv.x, Cv.y, Cv.z, Cv.w};
                #pragma unroll
                for (int j = 0; j < 4; ++j) {
                    const int n = nq * 4 + j;
                    float dA = __expf(del * Ar[n]);
                    h[n] = fmaf(dA, h[n], du * bb[j]);
                    y = fmaf(h[n], cc[j], y);
                }
            }
            y = fmaf(u, Dpv, y);
            gs_s[tid] = y * silu_f(zs_s[tid]);
        }
        __syncthreads();
    }
}

// ---------------------------------------------------------------------------
extern "C" void kernel_launch(void* const* d_in, const int* in_sizes, int n_in,
                              void* d_out, int out_size, void* d_ws, size_t ws_size,
                              hipStream_t stream) {
    const float* x      = (const float*)d_in[0];
    const float* W_in   = (const float*)d_in[1];
    const float* conv_w = (const float*)d_in[2];
    const float* conv_b = (const float*)d_in[3];
    const float* W_x    = (const float*)d_in[4];
    const float* W_dt   = (const float*)d_in[5];
    const float* b_dt   = (const float*)d_in[6];
    const float* A_log  = (const float*)d_in[7];
    const float* Dp     = (const float*)d_in[8];
    const float* W_out  = (const float*)d_in[9];
    float* out = (float*)d_out;

    float* base = (float*)d_ws;
    size_t off = 0;
    auto alloc = [&](size_t n) { float* pp = base + off; off += (n + 15) & ~(size_t)15; return pp; };
    unsigned* flags = (unsigned*)alloc(256);
    float* xbuf     = alloc((size_t)16 * 16 * 2 * 128);
    float* gbuf     = alloc(16 * 512);
    float* h_state  = alloc((size_t)16 * 512 * 16);
    float* dtBC255  = alloc(16 * 48);
    float* Sb       = alloc((size_t)128 * 512);
    float* Qb       = alloc((size_t)128 * 512 * 16);
    float* xi_pre   = alloc((size_t)4096 * 512);
    float* WcT      = alloc((size_t)512 * 1024);

    hipMemsetAsync(flags, 0, 256 * sizeof(unsigned), stream);
    hipLaunchKernelGGL(k_prefill_a, dim3(640), dim3(256), 0, stream,
                       x, W_in, W_out, WcT, xi_pre);
    hipLaunchKernelGGL(k_prefill_b, dim3(128), dim3(512), 0, stream,
                       xi_pre, conv_w, conv_b, W_x, W_dt, b_dt, A_log, Qb, Sb, dtBC255);
    hipLaunchKernelGGL(k_prefill_c, dim3(16), dim3(512), 0, stream,
                       x, W_in, Qb, Sb, dtBC255, xi_pre, conv_w, conv_b, A_log, Dp,
                       h_state, gbuf);
    hipLaunchKernelGGL(k_gen, dim3(256), dim3(512), 0, stream,
                       WcT, W_out, W_x, W_dt, conv_w, conv_b, b_dt, A_log, Dp,
                       xi_pre, h_state, gbuf, xbuf, flags, out);
}

// Round 9
// 339.040 us; speedup vs baseline: 1.5399x; 1.5399x over previous
//
#include <hip/hip_runtime.h>
#include <cmath>

#define DEV __device__ __forceinline__

constexpr int B_SZ = 16;
constexpr int LSEQ = 256;
constexpr int DM   = 256;   // d_model
constexpr int DI   = 512;   // d_inner
constexpr int TLEN = 16;

DEV float silu_f(float x)     { return x / (1.f + __expf(-x)); }
DEV float softplus_f(float x) { return log1pf(__expf(x)); }

// ---------------------------------------------------------------------------
// kA: blocks [0,128): fold Wc[j][d] = sum_m W_in[j][m] * W_out[m][d]
//     blocks [128,640): in-projection xi_pre = x^T @ W_in(x-part)^T
// ---------------------------------------------------------------------------
__global__ __launch_bounds__(256) void k_prefill_a(const float* __restrict__ x,
                                                   const float* __restrict__ W_in,
                                                   const float* __restrict__ W_out,
                                                   float* __restrict__ Wc,
                                                   float* __restrict__ xi_pre) {
    __shared__ float smem[2][32][68];
    const int tid = threadIdx.x;
    const int ty = tid >> 4, tx = tid & 15;
    float acc[4][4] = {};
    if (blockIdx.x < 128) {
        const int j0 = (int)(blockIdx.x & 15) * 64;
        const int d0 = (int)(blockIdx.x >> 4) * 64;
        float (*As)[68] = smem[0];
        float (*Bs)[68] = smem[1];
        for (int kc = 0; kc < DM; kc += 32) {
            for (int it = 0; it < 8; ++it) {
                int idx = it * 256 + tid;
                int jj = idx >> 5, kk = idx & 31;
                As[kk][jj] = W_in[(size_t)(j0 + jj) * DM + kc + kk];
            }
            for (int it = 0; it < 8; ++it) {
                int idx = it * 256 + tid;
                int kk = idx >> 6, dd = idx & 63;
                Bs[kk][dd] = W_out[(size_t)(kc + kk) * DI + d0 + dd];
            }
            __syncthreads();
            for (int kk = 0; kk < 32; ++kk) {
                float4 a4 = *(const float4*)&As[kk][ty * 4];
                float4 b4 = *(const float4*)&Bs[kk][tx * 4];
                float av[4] = {a4.x, a4.y, a4.z, a4.w};
                float bv[4] = {b4.x, b4.y, b4.z, b4.w};
                for (int i = 0; i < 4; ++i)
                    for (int j = 0; j < 4; ++j) acc[i][j] = fmaf(av[i], bv[j], acc[i][j]);
            }
            __syncthreads();
        }
        for (int i = 0; i < 4; ++i) {
            float4 v = make_float4(acc[i][0], acc[i][1], acc[i][2], acc[i][3]);
            *(float4*)&Wc[(size_t)(j0 + ty * 4 + i) * DI + d0 + tx * 4] = v;
        }
    } else {
        const int bid2 = (int)blockIdx.x - 128;
        const int bx = bid2 & 7, by = bid2 >> 3;
        const int row0 = by * 64;
        const int b = row0 >> 8, l0 = row0 & 255;
        const int j0 = bx * 64;
        float (*As)[68] = smem[0];
        float (*Ws)[68] = smem[1];
        const float* xb = x + (size_t)b * DM * LSEQ;
        for (int kc = 0; kc < DM; kc += 32) {
            for (int it = 0; it < 8; ++it) {
                int idx = it * 256 + tid;
                int kk = idx >> 6, li = idx & 63;
                As[kk][li] = xb[(kc + kk) * LSEQ + l0 + li];
            }
            for (int it = 0; it < 8; ++it) {
                int idx = it * 256 + tid;
                int jj = idx >> 5, kk = idx & 31;
                Ws[kk][jj] = W_in[(size_t)(j0 + jj) * DM + kc + kk];
            }
            __syncthreads();
            for (int kk = 0; kk < 32; ++kk) {
                float4 a4 = *(const float4*)&As[kk][ty * 4];
                float4 w4 = *(const float4*)&Ws[kk][tx * 4];
                float av[4] = {a4.x, a4.y, a4.z, a4.w};
                float wv[4] = {w4.x, w4.y, w4.z, w4.w};
                for (int i = 0; i < 4; ++i)
                    for (int j = 0; j < 4; ++j) acc[i][j] = fmaf(av[i], wv[j], acc[i][j]);
            }
            __syncthreads();
        }
        for (int i = 0; i < 4; ++i) {
            float4 v = make_float4(acc[i][0], acc[i][1], acc[i][2], acc[i][3]);
            *(float4*)&xi_pre[(size_t)(row0 + ty * 4 + i) * DI + j0 + tx * 4] = v;
        }
    }
}

// ---------------------------------------------------------------------------
// kB: fused conv+silu -> dtBC GEMM -> chunked scan (unchanged).
// ---------------------------------------------------------------------------
__global__ __launch_bounds__(512) void k_prefill_b(const float* __restrict__ xi_pre,
                                                   const float* __restrict__ conv_w,
                                                   const float* __restrict__ conv_b,
                                                   const float* __restrict__ W_x,
                                                   const float* __restrict__ W_dt,
                                                   const float* __restrict__ b_dt,
                                                   const float* __restrict__ A_log,
                                                   float* __restrict__ Qb,
                                                   float* __restrict__ Sb,
                                                   float* __restrict__ dtBC255) {
    __shared__ float As[32][516];
    __shared__ float Ws[48][129];
    __shared__ float dt_s[32][49];
    const int blk = blockIdx.x;
    const int b = blk >> 3, c = blk & 7;
    const int d = threadIdx.x;
    const int l0 = c * 32;
    {
        const float c0 = conv_w[d * 4 + 0], c1 = conv_w[d * 4 + 1];
        const float c2 = conv_w[d * 4 + 2], c3 = conv_w[d * 4 + 3];
        const float cbv = conv_b[d];
        float p0, p1, p2;
        int l;
        l = l0 - 3; p0 = (l >= 0) ? xi_pre[(size_t)(b * 256 + l) * DI + d] : 0.f;
        l = l0 - 2; p1 = (l >= 0) ? xi_pre[(size_t)(b * 256 + l) * DI + d] : 0.f;
        l = l0 - 1; p2 = (l >= 0) ? xi_pre[(size_t)(b * 256 + l) * DI + d] : 0.f;
        for (int ll = 0; ll < 32; ++ll) {
            float v = xi_pre[(size_t)(b * 256 + l0 + ll) * DI + d];
            As[ll][d] = silu_f(cbv + c0 * p0 + c1 * p1 + c2 * p2 + c3 * v);
            p0 = p1; p1 = p2; p2 = v;
        }
    }
    __syncthreads();
    {
        const int lr = d >> 4, rg = d & 15;
        float acc[3] = {};
        for (int kc = 0; kc < 4; ++kc) {
            for (int it = 0; it < 12; ++it) {
                int idx = it * 512 + d;
                int rr = idx >> 7, k = idx & 127;
                Ws[rr][k] = W_x[(size_t)rr * DI + kc * 128 + k];
            }
            __syncthreads();
            for (int k = 0; k < 128; ++k) {
                float a = As[lr][kc * 128 + k];
                acc[0] = fmaf(a, Ws[rg * 3 + 0][k], acc[0]);
                acc[1] = fmaf(a, Ws[rg * 3 + 1][k], acc[1]);
                acc[2] = fmaf(a, Ws[rg * 3 + 2][k], acc[2]);
            }
            __syncthreads();
        }
        dt_s[lr][rg * 3 + 0] = acc[0];
        dt_s[lr][rg * 3 + 1] = acc[1];
        dt_s[lr][rg * 3 + 2] = acc[2];
    }
    __syncthreads();
    {
        float Ar[16], Wd[16];
        for (int n = 0; n < 16; ++n) Ar[n] = -__expf(A_log[d * 16 + n]);
        for (int r = 0; r < 16; ++r) Wd[r] = W_dt[d * 16 + r];
        const float bd = b_dt[d];
        float q[16] = {};
        float Ssum = 0.f;
        for (int l = 0; l < 32; ++l) {
            float s = bd;
            for (int r = 0; r < 16; ++r) s = fmaf(dt_s[l][r], Wd[r], s);
            const float del = softplus_f(s);
            const float u = As[l][d];
            const float du = del * u;
            Ssum += del;
            for (int n = 0; n < 16; ++n) {
                float dA = __expf(del * Ar[n]);
                q[n] = fmaf(dA, q[n], du * dt_s[l][16 + n]);
            }
        }
        float* qo = Qb + ((size_t)blk * DI + d) * 16;
        for (int n = 0; n < 16; ++n) qo[n] = q[n];
        Sb[blk * DI + d] = Ssum;
    }
    if (c == 7 && d < 48) dtBC255[b * 48 + d] = dt_s[31][d];
}

// ---------------------------------------------------------------------------
// kC: compose chunks -> h(255), z(255) inline, gate -> gbuf (unchanged).
// ---------------------------------------------------------------------------
__global__ __launch_bounds__(512) void k_prefill_c(const float* __restrict__ x,
                                                   const float* __restrict__ W_in,
                                                   const float* __restrict__ Qb,
                                                   const float* __restrict__ Sb,
                                                   const float* __restrict__ dtBC255,
                                                   const float* __restrict__ xi_pre,
                                                   const float* __restrict__ conv_w,
                                                   const float* __restrict__ conv_b,
                                                   const float* __restrict__ A_log,
                                                   const float* __restrict__ Dp,
                                                   float* __restrict__ h_state,
                                                   float* __restrict__ gbuf) {
    __shared__ __align__(16) float xcol[256];
    const int b = blockIdx.x;
    const int d = threadIdx.x;
    if (d < 256) xcol[d] = x[(size_t)b * DM * LSEQ + d * LSEQ + 255];
    __syncthreads();
    float z = 0.f;
    {
        const float4* wr = (const float4*)&W_in[(size_t)(DI + d) * DM];
        const float4* xc4 = (const float4*)xcol;
        for (int k = 0; k < 64; ++k) {
            float4 w = wr[k], xx = xc4[k];
            z += w.x * xx.x + w.y * xx.y + w.z * xx.z + w.w * xx.w;
        }
    }
    float Ar[16];
    for (int n = 0; n < 16; ++n) Ar[n] = -__expf(A_log[d * 16 + n]);
    float h[16] = {};
    for (int c = 0; c < 8; ++c) {
        const int blk = b * 8 + c;
        const float S = Sb[blk * DI + d];
        const float* qv = Qb + ((size_t)blk * DI + d) * 16;
        for (int n = 0; n < 16; ++n) {
            float P = __expf(S * Ar[n]);
            h[n] = fmaf(P, h[n], qv[n]);
        }
    }
    float y = 0.f;
    for (int n = 0; n < 16; ++n) y = fmaf(h[n], dtBC255[b * 48 + 32 + n], y);
    float u;
    {
        float s = conv_b[d];
        for (int k = 0; k < 4; ++k)
            s = fmaf(conv_w[d * 4 + k], xi_pre[(size_t)(b * 256 + 252 + k) * DI + d], s);
        u = silu_f(s);
    }
    y = fmaf(u, Dp[d], y);
    gbuf[b * DI + d] = y * silu_f(z);
    float* ho = h_state + ((size_t)(b * DI + d)) * 16;
    for (int n = 0; n < 16; ++n) ho[n] = h[n];
}

// ---------------------------------------------------------------------------
// kD: persistent generation. 256 blocks = 16 batches x 16 slices, 512 thr.
// Wc slice in LDS with lane=row mapping (2 lanes/bank = conflict-free);
// gs operand is a pure wave broadcast. No register pinning, no scratch.
// Acquire poll (proven). 112-float post with partial dtBC.
// ---------------------------------------------------------------------------
__global__ __launch_bounds__(512) void k_gen(
    const float* __restrict__ Wc, const float* __restrict__ W_out,
    const float* __restrict__ W_x, const float* __restrict__ W_dt,
    const float* __restrict__ conv_w, const float* __restrict__ conv_b,
    const float* __restrict__ b_dt, const float* __restrict__ A_log,
    const float* __restrict__ Dp, const float* __restrict__ xi_pre,
    const float* __restrict__ h_state, const float* __restrict__ gbuf0,
    float* __restrict__ xbuf, unsigned* __restrict__ flags,
    float* __restrict__ out) {
    const int bid = blockIdx.x;
    const int b = bid & 15;     // all 16 blocks of batch b share bid%8 -> one XCD
    const int p = bid >> 4;
    const int tid = threadIdx.x;

    __shared__ float wc_s[64][516];             // rows 0..31 x-part, 32..63 z-part
    __shared__ float wxp[48][37];               // W_x cols [p*32, p*32+32)
    __shared__ __align__(16) float gs_s[512];
    __shared__ float xin_s[512];
    __shared__ float zs_s[512];
    __shared__ float red8[8][68];
    __shared__ float dpart[16][52];
    __shared__ __align__(16) float dtbc_s[48];
    __shared__ float post_s[112];
    __shared__ float hist[3][32];

    // ---- stage Wc slice into LDS (coalesced float4, conflict-free writes)
    for (int it = 0; it < 16; ++it) {
        int f4 = it * 512 + tid;               // 8192 float4s
        int rr = f4 >> 7;
        int c4 = (f4 & 127) * 4;
        int gr = (rr < 32) ? (p * 32 + rr) : (DI + p * 32 + (rr - 32));
        float4 v = *(const float4*)&Wc[(size_t)gr * DI + c4];
        *(float4*)&wc_s[rr][c4] = v;
    }
    for (int it = 0; it < 3; ++it) {
        int flat = it * 512 + tid;             // 1536 elems
        int rr = flat >> 5, cc = flat & 31;
        wxp[rr][cc] = W_x[(size_t)rr * DI + p * 32 + cc];
    }
    // W_out row-slice in registers (small; no pin needed at this pressure)
    const int orow_l = tid >> 5, osub = tid & 31;
    float wout[16];
    #pragma unroll
    for (int j = 0; j < 16; ++j)
        wout[j] = W_out[(size_t)(p * 16 + orow_l) * DI + osub + 32 * j];

    // per-thread scan state (d = tid)
    float wdt[16], Ar[16], h[16];
    {
        const float4* wp = (const float4*)&W_dt[tid * 16];
        const float4* ap = (const float4*)&A_log[tid * 16];
        const float4* hp = (const float4*)&h_state[((size_t)(b * DI + tid)) * 16];
        #pragma unroll
        for (int i = 0; i < 4; ++i) {
            float4 wv = wp[i], av = ap[i], hv = hp[i];
            wdt[4*i+0]=wv.x; wdt[4*i+1]=wv.y; wdt[4*i+2]=wv.z; wdt[4*i+3]=wv.w;
            Ar[4*i+0]=-__expf(av.x); Ar[4*i+1]=-__expf(av.y);
            Ar[4*i+2]=-__expf(av.z); Ar[4*i+3]=-__expf(av.w);
            h[4*i+0]=hv.x; h[4*i+1]=hv.y; h[4*i+2]=hv.z; h[4*i+3]=hv.w;
        }
    }
    const float bd = b_dt[tid];
    const float Dpv = Dp[tid];
    float cw0 = 0, cw1 = 0, cw2 = 0, cw3 = 0, cb = 0;
    if (tid < 32) {
        const int d = p * 32 + tid;
        cw0 = conv_w[d * 4 + 0]; cw1 = conv_w[d * 4 + 1];
        cw2 = conv_w[d * 4 + 2]; cw3 = conv_w[d * 4 + 3];
        cb  = conv_b[d];
        for (int k = 0; k < 3; ++k)
            hist[k][tid] = xi_pre[(size_t)(b * 256 + 253 + k) * DI + d];
    }
    gs_s[tid] = gbuf0[b * DI + tid];
    __syncthreads();

    const int r = tid & 63, q = tid >> 6;      // GEMV mapping: lane=row, wave=K-chunk

    for (int t = 0; t < TLEN; ++t) {
        if (t < TLEN - 1) {
            // A: preconv GEMV — wc_s lane-row reads (2/bank free), gs broadcast
            {
                const float4* wrow = (const float4*)&wc_s[r][q * 64];
                const float4* g4   = (const float4*)&gs_s[q * 64];
                float s = 0.f;
                #pragma unroll
                for (int kk = 0; kk < 16; ++kk) {
                    float4 wv = wrow[kk], g = g4[kk];
                    s = fmaf(wv.x, g.x, s);
                    s = fmaf(wv.y, g.y, s);
                    s = fmaf(wv.z, g.z, s);
                    s = fmaf(wv.w, g.w, s);
                }
                red8[q][r] = s;
            }
            __syncthreads();
            // B1: reduce; conv+silu / z -> post_s[0..64)
            if (tid < 64) {
                float v = 0.f;
                #pragma unroll
                for (int ss = 0; ss < 8; ++ss) v += red8[ss][tid];
                if (tid < 32) {
                    float xc = cb;
                    xc = fmaf(cw0, hist[t % 3][tid], xc);
                    xc = fmaf(cw1, hist[(t + 1) % 3][tid], xc);
                    xc = fmaf(cw2, hist[(t + 2) % 3][tid], xc);
                    xc = fmaf(cw3, v, xc);
                    hist[t % 3][tid] = v;
                    post_s[tid] = silu_f(xc);
                } else {
                    post_s[tid] = v;
                }
            }
            __syncthreads();
            // B2: own dtBC partial (48 rows x own 32 xin) -> post_s[64..112)
            if (tid < 384) {
                const int rr = tid >> 3, qq = tid & 7;
                const float* wr = &wxp[rr][qq * 4];
                const float* xv = &post_s[qq * 4];
                float s = wr[0]*xv[0] + wr[1]*xv[1] + wr[2]*xv[2] + wr[3]*xv[3];
                s += __shfl_down(s, 4); s += __shfl_down(s, 2); s += __shfl_down(s, 1);
                if (qq == 0) post_s[64 + rr] = s;
            }
            __syncthreads();
            // post 112 floats + release flag
            if (tid < 112) {
                __hip_atomic_store(&xbuf[((size_t)((b * 16 + p) * 2 + (t & 1))) * 128 + tid],
                                   post_s[tid], __ATOMIC_RELAXED, __HIP_MEMORY_SCOPE_AGENT);
            }
            __syncthreads();   // drain stores before flag
            if (tid == 0)
                __hip_atomic_store(&flags[b * 16 + p], (unsigned)(t + 1),
                                   __ATOMIC_RELEASE, __HIP_MEMORY_SCOPE_AGENT);
        }
        // C: output token t (wout regs x gs broadcast; overlaps peers' posting)
        {
            float s = 0.f;
            #pragma unroll
            for (int j = 0; j < 16; ++j) s = fmaf(wout[j], gs_s[osub + 32 * j], s);
            s += __shfl_down(s, 16); s += __shfl_down(s, 8);
            s += __shfl_down(s, 4);  s += __shfl_down(s, 2); s += __shfl_down(s, 1);
            if (osub == 0) out[(size_t)(b * 256 + p * 16 + orow_l) * TLEN + t] = s;
        }
        if (t == TLEN - 1) return;

        // D: acquire poll (per-iteration acquire -> L1 invalidate, proven fast)
        if (tid < 16) {
            while (__hip_atomic_load(&flags[b * 16 + tid],
                                     __ATOMIC_ACQUIRE, __HIP_MEMORY_SCOPE_AGENT)
                   < (unsigned)(t + 1))
                __builtin_amdgcn_s_sleep(1);
        }
        __syncthreads();
        // E: gather 16 x 112
        #pragma unroll
        for (int i = 0; i < 4; ++i) {
            int idx = i * 512 + tid;
            int qg = idx >> 7, pos = idx & 127;
            if (pos < 112) {
                float v = __hip_atomic_load(
                    xbuf + ((size_t)((b * 16 + qg) * 2 + (t & 1))) * 128 + pos,
                    __ATOMIC_RELAXED, __HIP_MEMORY_SCOPE_AGENT);
                if (pos < 32)      xin_s[qg * 32 + pos] = v;
                else if (pos < 64) zs_s[qg * 32 + pos - 32] = v;
                else               dpart[qg][pos - 64] = v;
            }
        }
        __syncthreads();
        // F: reduce dtbc partials
        if (tid < 48) {
            float s = 0.f;
            #pragma unroll
            for (int qg = 0; qg < 16; ++qg) s += dpart[qg][tid];
            dtbc_s[tid] = s;
        }
        __syncthreads();
        // G: replicated scan step (dtbc via float4 broadcasts)
        {
            const float4* dt4 = (const float4*)dtbc_s;
            float dt_l = bd;
            #pragma unroll
            for (int i = 0; i < 4; ++i) {
                float4 dv = dt4[i];
                dt_l = fmaf(dv.x, wdt[4*i+0], dt_l);
                dt_l = fmaf(dv.y, wdt[4*i+1], dt_l);
                dt_l = fmaf(dv.z, wdt[4*i+2], dt_l);
                dt_l = fmaf(dv.w, wdt[4*i+3], dt_l);
            }
            const float del = softplus_f(dt_l);
            const float u = xin_s[tid];
            const float du = del * u;
            float y = 0.f;
            #pragma unroll
            for (int nq = 0; nq < 4; ++nq) {
                float4 Bv = dt4[4 + nq];
                float4 Cv = dt4[8 + nq];
                float bb[4] = {Bv.x, Bv.y, Bv.z, Bv.w};
                float cc[4] = {Cv.x, Cv.y, Cv.z, Cv.w};
                #pragma unroll
                for (int j = 0; j < 4; ++j) {
                    const int n = nq * 4 + j;
                    float dA = __expf(del * Ar[n]);
                    h[n] = fmaf(dA, h[n], du * bb[j]);
                    y = fmaf(h[n], cc[j], y);
                }
            }
            y = fmaf(u, Dpv, y);
            gs_s[tid] = y * silu_f(zs_s[tid]);
        }
        __syncthreads();
    }
}

// ---------------------------------------------------------------------------
extern "C" void kernel_launch(void* const* d_in, const int* in_sizes, int n_in,
                              void* d_out, int out_size, void* d_ws, size_t ws_size,
                              hipStream_t stream) {
    const float* x      = (const float*)d_in[0];
    const float* W_in   = (const float*)d_in[1];
    const float* conv_w = (const float*)d_in[2];
    const float* conv_b = (const float*)d_in[3];
    const float* W_x    = (const float*)d_in[4];
    const float* W_dt   = (const float*)d_in[5];
    const float* b_dt   = (const float*)d_in[6];
    const float* A_log  = (const float*)d_in[7];
    const float* Dp     = (const float*)d_in[8];
    const float* W_out  = (const float*)d_in[9];
    float* out = (float*)d_out;

    float* base = (float*)d_ws;
    size_t off = 0;
    auto alloc = [&](size_t n) { float* pp = base + off; off += (n + 15) & ~(size_t)15; return pp; };
    unsigned* flags = (unsigned*)alloc(256);
    float* xbuf     = alloc((size_t)16 * 16 * 2 * 128);
    float* gbuf     = alloc(16 * 512);
    float* h_state  = alloc((size_t)16 * 512 * 16);
    float* dtBC255  = alloc(16 * 48);
    float* Sb       = alloc((size_t)128 * 512);
    float* Qb       = alloc((size_t)128 * 512 * 16);
    float* xi_pre   = alloc((size_t)4096 * 512);
    float* Wc       = alloc((size_t)1024 * 512);

    hipMemsetAsync(flags, 0, 256 * sizeof(unsigned), stream);
    hipLaunchKernelGGL(k_prefill_a, dim3(640), dim3(256), 0, stream,
                       x, W_in, W_out, Wc, xi_pre);
    hipLaunchKernelGGL(k_prefill_b, dim3(128), dim3(512), 0, stream,
                       xi_pre, conv_w, conv_b, W_x, W_dt, b_dt, A_log, Qb, Sb, dtBC255);
    hipLaunchKernelGGL(k_prefill_c, dim3(16), dim3(512), 0, stream,
                       x, W_in, Qb, Sb, dtBC255, xi_pre, conv_w, conv_b, A_log, Dp,
                       h_state, gbuf);
    hipLaunchKernelGGL(k_gen, dim3(256), dim3(512), 0, stream,
                       Wc, W_out, W_x, W_dt, conv_w, conv_b, b_dt, A_log, Dp,
                       xi_pre, h_state, gbuf, xbuf, flags, out);
}